// Round 12
// baseline (996.019 us; speedup 1.0000x reference)
//
#include <hip/hip_runtime.h>
#include <hip/hip_bf16.h>

#define N_NODES 25000
#define N_EDGES 200000
#define N_GRAPHS 64
#define HID 128
#define DEPTH 5

typedef _Float16 half8 __attribute__((ext_vector_type(8)));
typedef _Float16 half2v __attribute__((ext_vector_type(2)));
typedef float f32x4 __attribute__((ext_vector_type(4)));

__device__ inline half8 pack8(float4 a, float4 b) {
    half8 r;
    r[0] = (_Float16)a.x; r[1] = (_Float16)a.y; r[2] = (_Float16)a.z; r[3] = (_Float16)a.w;
    r[4] = (_Float16)b.x; r[5] = (_Float16)b.y; r[6] = (_Float16)b.z; r[7] = (_Float16)b.w;
    return r;
}

// ---------------- embed ----------------
__global__ void embed_kernel(const float* __restrict__ x, const float* __restrict__ W,
                             const float* __restrict__ b, float* __restrict__ h) {
    for (int i = blockIdx.x * blockDim.x + threadIdx.x; i < N_NODES * HID;
         i += gridDim.x * blockDim.x) {
        int n = i >> 7, j = i & 127;
        float acc = b[j];
        #pragma unroll
        for (int k = 0; k < 16; k++) acc += x[n * 16 + k] * W[k * 128 + j];
        h[i] = acc;
    }
}

// ---------------- weight prep: f32 -> f16 arenas in EXACT LDS image layouts ----------------
__global__ void prep_kernel(const float* __restrict__ msg_W1, const float* __restrict__ msg_W2,
                            const float* __restrict__ upd_W1, const float* __restrict__ upd_W2,
                            _Float16* __restrict__ usW, _Float16* __restrict__ eW2,
                            _Float16* __restrict__ uW1, _Float16* __restrict__ uW2) {
    int i = blockIdx.x * blockDim.x + threadIdx.x;
    const int N_US = DEPTH * 32768, N_E2 = DEPTH * 16384, N_U1 = DEPTH * 32768, N_U2 = DEPTH * 16384;
    if (i < N_US) {
        int l = i >> 15, r = i & 32767;
        int j = r & 7, low6 = (r >> 3) & 63, kq = (low6 >> 4) & 3, s_ = low6 & 15;
        int rest = r >> 9, tt = rest & 15, kb = rest >> 4;
        int kk = (kb << 5) | (kq << 3) | j;
        int uh = tt >> 3, t = tt & 7, cc = s_ * 8 + t;
        const float* W1 = msg_W1 + (size_t)l * 257 * 128;
        usW[i] = (_Float16)(uh ? W1[(128 + kk) * 128 + cc] : W1[kk * 128 + cc]);
        return;
    }
    i -= N_US;
    if (i < N_E2) {
        int l = i >> 14, r = i & 16383;
        int j = r & 7, low6 = (r >> 3) & 63, kq = (low6 >> 4) & 3, s_ = low6 & 15;
        int rest = r >> 9, t = rest & 7, kb = rest >> 3;
        int k = (kb << 5) | (kq << 3) | j, c = s_ * 8 + t;
        eW2[i] = (_Float16)msg_W2[(size_t)l * 16384 + k * 128 + c];
        return;
    }
    i -= N_E2;
    if (i < N_U1) {
        int l = i >> 15, r = i & 32767;
        int j = r & 7, low6 = (r >> 3) & 63, kq = (low6 >> 4) & 3, s_ = low6 & 15;
        int rest = r >> 9, t = rest & 7, kb = rest >> 3;   // kb 0..7
        int k = (kb << 5) | (kq << 3) | j, c = s_ * 8 + t;
        uW1[i] = (_Float16)upd_W1[(size_t)l * 32768 + k * 128 + c];
        return;
    }
    i -= N_U1;
    if (i < N_U2) {
        int l = i >> 14, r = i & 16383;
        int j = r & 7, low6 = (r >> 3) & 63, kq = (low6 >> 4) & 3, s_ = low6 & 15;
        int rest = r >> 9, t = rest & 7, kb = rest >> 3;
        int k = (kb << 5) | (kq << 3) | j, c = s_ * 8 + t;
        uW2[i] = (_Float16)upd_W2[(size_t)l * 16384 + k * 128 + c];
    }
}

// ---------------- CSR build ----------------
__global__ void hist_kernel(const int* __restrict__ ei, int* __restrict__ cnt) {
    int e = blockIdx.x * blockDim.x + threadIdx.x;
    if (e < N_EDGES) atomicAdd(&cnt[ei[N_EDGES + e]], 1);
}

__global__ __launch_bounds__(1024)
void scan_kernel(const int* cnt, int* rowptr, int* cursor) {   // cnt may alias cursor
    __shared__ int swsum[16];
    __shared__ int stot;
    const int tid = threadIdx.x, wave = tid >> 6, lane = tid & 63;
    int carry = 0;
    for (int base = 0; base < N_NODES; base += 1024) {
        int i = base + tid;
        int v0 = (i < N_NODES) ? cnt[i] : 0;
        int v = v0;
        #pragma unroll
        for (int d = 1; d < 64; d <<= 1) {
            int t = __shfl_up(v, d, 64);
            if (lane >= d) v += t;
        }
        if (lane == 63) swsum[wave] = v;
        __syncthreads();
        if (wave == 0) {
            int sv = (lane < 16) ? swsum[lane] : 0;
            int si = sv;
            #pragma unroll
            for (int d = 1; d < 16; d <<= 1) {
                int t = __shfl_up(si, d, 64);
                if (lane >= d) si += t;
            }
            if (lane < 16) swsum[lane] = si - sv;
            if (lane == 15) stot = si;
        }
        __syncthreads();
        int excl = v - v0 + swsum[wave] + carry;
        if (i < N_NODES) { rowptr[i] = excl; cursor[i] = excl; }
        carry += stot;
        __syncthreads();
    }
    if (tid == 0) rowptr[N_NODES] = carry;
}

__global__ void scatter_kernel(const int* __restrict__ ei, const float* __restrict__ pos,
                               int* __restrict__ cursor, int* __restrict__ src_s,
                               int* __restrict__ dst_s, float* __restrict__ dist_s) {
    int e = blockIdx.x * blockDim.x + threadIdx.x;
    if (e < N_EDGES) {
        int s = ei[e], d = ei[N_EDGES + e];
        int p = atomicAdd(&cursor[d], 1);
        src_s[p] = s; dst_s[p] = d;
        float dx = pos[d * 3 + 0] - pos[s * 3 + 0];
        float dy = pos[d * 3 + 1] - pos[s * 3 + 1];
        float dz = pos[d * 3 + 2] - pos[s * 3 + 2];
        dist_s[p] = sqrtf(dx * dx + dy * dy + dz * dz);
    }
}

// ---------------- US precompute (arena-staged f16 weights) + agg zeroing ----------------
__global__ __launch_bounds__(512, 2)
void us_kernel(const float* __restrict__ h, const _Float16* __restrict__ Wf,
               const float* __restrict__ bias1,
               _Float16* __restrict__ U, _Float16* __restrict__ S,
               float* __restrict__ agg) {
    __shared__ __attribute__((aligned(16))) _Float16 sW[32768];   // [kb(4)][tt(16)][lane(64)][j(8)]
    __shared__ float sB1[128];
    const int tid = threadIdx.x;
    {
        const half8* wsrc = (const half8*)Wf;
        half8* wdst = (half8*)sW;
        #pragma unroll
        for (int idx = tid; idx < 4096; idx += 512) wdst[idx] = wsrc[idx];
    }
    if (tid < 128) sB1[tid] = bias1[tid];
    __syncthreads();

    const int w = tid >> 6, lane = tid & 63, quad = lane >> 4, s = lane & 15;
    float b1c[8];
    #pragma unroll
    for (int t = 0; t < 8; t++) b1c[t] = sB1[s * 8 + t];

    const int gw = blockIdx.x * 8 + w, nwaves = gridDim.x * 8;
    const int nwt = (N_NODES + 15) >> 4;
    for (int wt = gw; wt < nwt; wt += nwaves) {
        const int nbase = wt << 4;
        int n = nbase + s; if (n >= N_NODES) n = N_NODES - 1;

        half8 af[4];
        #pragma unroll
        for (int kb = 0; kb < 4; kb++) {
            const float* rp = h + (size_t)n * 128 + kb * 32 + quad * 8;
            af[kb] = pack8(*(const float4*)rp, *(const float4*)(rp + 4));
        }

        #pragma unroll
        for (int uhalf = 0; uhalf < 2; uhalf++) {
            f32x4 acc[8];
            #pragma unroll
            for (int t = 0; t < 8; t++) { f32x4 z = {0.f, 0.f, 0.f, 0.f}; acc[t] = z; }
            #pragma unroll
            for (int kb = 0; kb < 4; kb++) {
                #pragma unroll
                for (int t = 0; t < 8; t++) {
                    half8 bf = *(const half8*)(&sW[((((kb << 4) + (uhalf * 8 + t)) << 6) + lane) * 8]);
                    acc[t] = __builtin_amdgcn_mfma_f32_16x16x32_f16(af[kb], bf, acc[t], 0, 0, 0);
                }
            }
            _Float16* dstbuf = uhalf ? S : U;
            #pragma unroll
            for (int r = 0; r < 4; r++) {
                int nn = nbase + quad * 4 + r;
                if (nn < N_NODES) {
                    half8 ov;
                    #pragma unroll
                    for (int t = 0; t < 8; t++)
                        ov[t] = (_Float16)(acc[t][r] + (uhalf ? 0.f : b1c[t]));
                    *(half8*)(&dstbuf[(size_t)nn * 128 + s * 8]) = ov;
                    if (uhalf == 0) {
                        // zero agg for this node's column slice (replaces hipMemsetAsync)
                        float4 z4 = {0.f, 0.f, 0.f, 0.f};
                        float* ap = agg + (size_t)nn * 128 + s * 8;
                        *(float4*)ap = z4;
                        *(float4*)(ap + 4) = z4;
                    }
                }
            }
        }
    }
}

// ---------------- edge kernel: M=16/wave, 3 blocks/CU, run-segmented atomic scatter ----------------
// N_EDGES % 16 == 0 -> all 16-edge tiles are exact.
__global__ __launch_bounds__(256, 3)
void edge_kernel(const _Float16* __restrict__ U, const _Float16* __restrict__ S,
                 const float* __restrict__ dist_s, const int* __restrict__ src_s,
                 const int* __restrict__ dst_s,
                 const float* __restrict__ w256, const float* __restrict__ gam1,
                 const float* __restrict__ bet1,
                 const _Float16* __restrict__ W2f, const float* __restrict__ bias2,
                 const float* __restrict__ gam2, const float* __restrict__ bet2,
                 float* __restrict__ agg) {
    __shared__ __attribute__((aligned(16))) _Float16 sW2[16384];  // [kb(4)][t(8)][lane(64)][j(8)]
    __shared__ _Float16 sM1[8704];     // 4 waves x [16 rows][136]
    __shared__ int   sDstA[4][18];     // 17 dsts (incl. next-tile first) per wave
    __shared__ int   sSrcA[4][16];
    __shared__ float sDistA[4][16];

    const int tid = threadIdx.x;
    {
        const half8* wsrc = (const half8*)W2f;
        half8* wdst = (half8*)sW2;
        #pragma unroll
        for (int idx = tid; idx < 2048; idx += 256) wdst[idx] = wsrc[idx];
    }
    __syncthreads();

    const int w = tid >> 6, lane = tid & 63, quad = lane >> 4, s = lane & 15;
    _Float16* myM1 = &sM1[w * (16 * 136)];
    int*   sDst  = sDstA[w];
    int*   sSrc  = sSrcA[w];
    float* sDist = sDistA[w];

    // LN params straight to registers (no LDS broadcast; saves 3 KB LDS -> 3 blk/CU)
    float w256c[8], g1c[8], be1c[8], b2c[8], g2c[8], be2c[8];
    #pragma unroll
    for (int t = 0; t < 8; t++) {
        int c = s * 8 + t;
        w256c[t] = w256[c]; g1c[t] = gam1[c]; be1c[t] = bet1[c];
        b2c[t] = bias2[c]; g2c[t] = gam2[c]; be2c[t] = bet2[c];
    }

    const int gw = blockIdx.x * 4 + w, nwaves = gridDim.x * 4;
    const int ewt = N_EDGES >> 4;   // 12500, exact
    for (int wt = gw; wt < ewt; wt += nwaves) {
        const int ebase = wt << 4;

        // phase 0: stage indices/dists into per-wave LDS (one coalesced pass)
        if (lane <= 16) {
            int e = ebase + lane;
            sDst[lane] = (e < N_EDGES) ? dst_s[e] : -1;
        } else if (lane < 33) {
            sSrc[lane - 17] = src_s[ebase + lane - 17];
        } else if (lane < 49) {
            sDist[lane - 33] = dist_s[ebase + lane - 33];
        }
        // run-boundary mask over 16 rows (bit r: row r last of its dst-run in tile)
        bool bnd = (lane < 16) && (sDst[lane] != sDst[lane + 1]);
        unsigned mask = (unsigned)(__ballot(bnd) & 0xffffull);
        mask |= 0x8000u;   // always flush at tile end (runs spanning tiles)

        // phase A: gather U/S rows (8 outstanding 16B loads)
        float distA[4];
        half8 u8A[4], s8A[4];
        #pragma unroll
        for (int i = 0; i < 4; i++) {
            int row = quad * 4 + i;
            int d = sDst[row], si = sSrc[row];
            distA[i] = sDist[row];
            u8A[i] = *(const half8*)(&U[(size_t)d * 128 + s * 8]);
            s8A[i] = *(const half8*)(&S[(size_t)si * 128 + s * 8]);
        }

        // phase B: LN + relu -> myM1 (per-wave; in-order DS pipe, no barrier)
        #pragma unroll
        for (int i = 0; i < 4; i++) {
            float v[8], sum = 0.f, sq = 0.f;
            #pragma unroll
            for (int t = 0; t < 8; t++) {
                v[t] = (float)u8A[i][t] + (float)s8A[i][t] + distA[i] * w256c[t];
                sum += v[t]; sq += v[t] * v[t];
            }
            #pragma unroll
            for (int m = 1; m < 16; m <<= 1) {
                sum += __shfl_xor(sum, m, 64);
                sq  += __shfl_xor(sq, m, 64);
            }
            float mean = sum * (1.f / 128.f);
            float var = sq * (1.f / 128.f) - mean * mean;
            float rstd = rsqrtf(var + 1e-5f);
            half8 hv;
            #pragma unroll
            for (int t = 0; t < 8; t++) {
                float y = (v[t] - mean) * rstd * g1c[t] + be1c[t];
                hv[t] = (_Float16)fmaxf(y, 0.f);
            }
            *(half8*)(&myM1[(quad * 4 + i) * 136 + s * 8]) = hv;
        }

        // GEMM2 (M=16)
        f32x4 acc2[8];
        #pragma unroll
        for (int t = 0; t < 8; t++) { f32x4 z = {0.f, 0.f, 0.f, 0.f}; acc2[t] = z; }
        #pragma unroll
        for (int kb = 0; kb < 4; kb++) {
            half8 af = *(const half8*)(&myM1[s * 136 + kb * 32 + quad * 8]);
            #pragma unroll
            for (int t = 0; t < 8; t++) {
                half8 bf = *(const half8*)(&sW2[(((kb << 3) + t) * 64 + lane) * 8]);
                acc2[t] = __builtin_amdgcn_mfma_f32_16x16x32_f16(af, bf, acc2[t], 0, 0, 0);
            }
        }

        // epilogue 2: LN ; relu ; m2 rows -> myM1 (overwrite m1; GEMM2 reads done)
        #pragma unroll
        for (int r = 0; r < 4; r++) {
            float v[8], sum = 0.f, sq = 0.f;
            #pragma unroll
            for (int t = 0; t < 8; t++) {
                v[t] = acc2[t][r] + b2c[t];
                sum += v[t]; sq += v[t] * v[t];
            }
            #pragma unroll
            for (int m = 1; m < 16; m <<= 1) {
                sum += __shfl_xor(sum, m, 64);
                sq  += __shfl_xor(sq, m, 64);
            }
            float mean = sum * (1.f / 128.f);
            float var = sq * (1.f / 128.f) - mean * mean;
            float rstd = rsqrtf(var + 1e-5f);
            half8 hv;
            #pragma unroll
            for (int t = 0; t < 8; t++) {
                float y = (v[t] - mean) * rstd * g2c[t] + be2c[t];
                hv[t] = (_Float16)fmaxf(y, 0.f);
            }
            *(half8*)(&myM1[(quad * 4 + r) * 136 + s * 8]) = hv;
        }

        // phase C: run-segmented reduction over 16 rows; lane owns cols {2*lane, 2*lane+1}
        {
            const int col2 = lane * 2;
            half2v acc; acc[0] = (_Float16)0.f; acc[1] = (_Float16)0.f;
            for (int row = 0; row < 16; row++) {
                half2v v = *(const half2v*)(&myM1[row * 136 + col2]);
                acc += v;
                if ((mask >> row) & 1u) {                 // wave-uniform
                    int d = sDst[row];                    // LDS broadcast
                    float a0 = (float)acc[0], a1 = (float)acc[1];
                    if (a0 != 0.f) atomicAdd(&agg[(size_t)d * 128 + col2], a0);
                    if (a1 != 0.f) atomicAdd(&agg[(size_t)d * 128 + col2 + 1], a1);
                    acc[0] = (_Float16)0.f; acc[1] = (_Float16)0.f;
                }
            }
        }
    }
}

// ---------------- upd: node-MLP + residual (arena-staged f16 weights) ----------------
__global__ __launch_bounds__(512, 1)
void upd_kernel(float* __restrict__ h, const float* __restrict__ agg,
                const _Float16* __restrict__ W1f, const float* __restrict__ bias1,
                const float* __restrict__ gam1, const float* __restrict__ bet1,
                const _Float16* __restrict__ W2f, const float* __restrict__ bias2,
                const float* __restrict__ gam2, const float* __restrict__ bet2) {
    __shared__ __attribute__((aligned(16))) _Float16 sW1[32768];
    __shared__ __attribute__((aligned(16))) _Float16 sW2[16384];
    __shared__ _Float16 sM1[17408];   // 8 waves x [16 rows][136]
    __shared__ float sB[768];

    const int tid = threadIdx.x;
    {
        const half8* w1src = (const half8*)W1f;
        half8* w1dst = (half8*)sW1;
        #pragma unroll
        for (int idx = tid; idx < 4096; idx += 512) w1dst[idx] = w1src[idx];
        const half8* w2src = (const half8*)W2f;
        half8* w2dst = (half8*)sW2;
        #pragma unroll
        for (int idx = tid; idx < 2048; idx += 512) w2dst[idx] = w2src[idx];
    }
    if (tid < 128) {
        sB[tid] = bias1[tid]; sB[128 + tid] = gam1[tid]; sB[256 + tid] = bet1[tid];
        sB[384 + tid] = bias2[tid]; sB[512 + tid] = gam2[tid]; sB[640 + tid] = bet2[tid];
    }
    __syncthreads();

    const int w = tid >> 6, lane = tid & 63, quad = lane >> 4, s = lane & 15;
    _Float16* myM1 = &sM1[w * (16 * 136)];

    float b1c[8], g1c[8], be1c[8], b2c[8], g2c[8], be2c[8];
    #pragma unroll
    for (int t = 0; t < 8; t++) {
        int c = s * 8 + t;
        b1c[t] = sB[c]; g1c[t] = sB[128 + c]; be1c[t] = sB[256 + c];
        b2c[t] = sB[384 + c]; g2c[t] = sB[512 + c]; be2c[t] = sB[640 + c];
    }

    const int gw = blockIdx.x * 8 + w, nwaves = gridDim.x * 8;
    const int nwt = (N_NODES + 15) >> 4;
    for (int wt = gw; wt < nwt; wt += nwaves) {
        const int nbase = wt << 4;
        int n = nbase + s; if (n >= N_NODES) n = N_NODES - 1;

        // GEMM1: A = [h[n] | agg[n]] straight from global f32
        f32x4 acc[8];
        #pragma unroll
        for (int t = 0; t < 8; t++) { f32x4 z = {0.f, 0.f, 0.f, 0.f}; acc[t] = z; }
        #pragma unroll
        for (int kb = 0; kb < 8; kb++) {
            const float* rp = (kb < 4) ? (h + (size_t)n * 128 + kb * 32 + quad * 8)
                                       : (agg + (size_t)n * 128 + (kb - 4) * 32 + quad * 8);
            half8 af = pack8(*(const float4*)rp, *(const float4*)(rp + 4));
            #pragma unroll
            for (int t = 0; t < 8; t++) {
                half8 bf = *(const half8*)(&sW1[(((kb << 3) + t) * 64 + lane) * 8]);
                acc[t] = __builtin_amdgcn_mfma_f32_16x16x32_f16(af, bf, acc[t], 0, 0, 0);
            }
        }

        // epilogue 1: LN ; relu ; -> myM1
        #pragma unroll
        for (int r = 0; r < 4; r++) {
            float v[8], sum = 0.f, sq = 0.f;
            #pragma unroll
            for (int t = 0; t < 8; t++) {
                v[t] = acc[t][r] + b1c[t];
                sum += v[t]; sq += v[t] * v[t];
            }
            #pragma unroll
            for (int m = 1; m < 16; m <<= 1) {
                sum += __shfl_xor(sum, m, 64);
                sq  += __shfl_xor(sq, m, 64);
            }
            float mean = sum * (1.f / 128.f);
            float var = sq * (1.f / 128.f) - mean * mean;
            float rstd = rsqrtf(var + 1e-5f);
            half8 hv;
            #pragma unroll
            for (int t = 0; t < 8; t++) {
                float y = (v[t] - mean) * rstd * g1c[t] + be1c[t];
                hv[t] = (_Float16)fmaxf(y, 0.f);
            }
            *(half8*)(&myM1[(quad * 4 + r) * 136 + s * 8]) = hv;
        }

        // GEMM2
        f32x4 acc2[8];
        #pragma unroll
        for (int t = 0; t < 8; t++) { f32x4 z = {0.f, 0.f, 0.f, 0.f}; acc2[t] = z; }
        #pragma unroll
        for (int kb = 0; kb < 4; kb++) {
            half8 af = *(const half8*)(&myM1[s * 136 + kb * 32 + quad * 8]);
            #pragma unroll
            for (int t = 0; t < 8; t++) {
                half8 bf = *(const half8*)(&sW2[(((kb << 3) + t) * 64 + lane) * 8]);
                acc2[t] = __builtin_amdgcn_mfma_f32_16x16x32_f16(af, bf, acc2[t], 0, 0, 0);
            }
        }

        // epilogue 2: LN ; relu ; h += u
        #pragma unroll
        for (int r = 0; r < 4; r++) {
            int nn = nbase + quad * 4 + r;
            float v[8], sum = 0.f, sq = 0.f;
            #pragma unroll
            for (int t = 0; t < 8; t++) {
                v[t] = acc2[t][r] + b2c[t];
                sum += v[t]; sq += v[t] * v[t];
            }
            #pragma unroll
            for (int m = 1; m < 16; m <<= 1) {
                sum += __shfl_xor(sum, m, 64);
                sq  += __shfl_xor(sq, m, 64);
            }
            float mean = sum * (1.f / 128.f);
            float var = sq * (1.f / 128.f) - mean * mean;
            float rstd = rsqrtf(var + 1e-5f);
            if (nn < N_NODES) {
                float* hp = h + (size_t)nn * 128 + s * 8;
                float4 h0 = *(float4*)hp;
                float4 h1 = *(float4*)(hp + 4);
                float y[8];
                #pragma unroll
                for (int t = 0; t < 8; t++) {
                    float u = (v[t] - mean) * rstd * g2c[t] + be2c[t];
                    y[t] = fmaxf(u, 0.f);
                }
                h0.x += y[0]; h0.y += y[1]; h0.z += y[2]; h0.w += y[3];
                h1.x += y[4]; h1.y += y[5]; h1.z += y[6]; h1.w += y[7];
                *(float4*)hp = h0;
                *(float4*)(hp + 4) = h1;
            }
        }
    }
}

// ---------------- pool (parallel, segmented + atomics) ----------------
__global__ void pool_kernel(const float* __restrict__ h, const int* __restrict__ batch,
                            float* __restrict__ g) {
    const int CHUNK = 125;
    int blo = blockIdx.x * CHUNK;
    int bhi = blo + CHUNK; if (bhi > N_NODES) bhi = N_NODES;
    int j = threadIdx.x & 127;
    int half = threadIdx.x >> 7;
    float acc = 0.f; int cur = -1;
    for (int n = blo + half; n < bhi; n += 2) {
        int b = batch[n];
        if (b != cur) {
            if (cur >= 0) atomicAdd(&g[cur * 128 + j], acc);
            cur = b; acc = 0.f;
        }
        acc += h[(size_t)n * 128 + j];
    }
    if (cur >= 0) atomicAdd(&g[cur * 128 + j], acc);
}

// ---------------- pred ----------------
__global__ void pred_kernel(const float* __restrict__ g, const float* __restrict__ W1,
                            const float* __restrict__ b1, const float* __restrict__ W2,
                            const float* __restrict__ b2, float* __restrict__ out) {
    int b = blockIdx.x, j = threadIdx.x;
    float t = b1[j];
    for (int k = 0; k < 128; k++) t += g[b * 128 + k] * W1[k * 128 + j];
    t = fmaxf(t, 0.f);
    __shared__ float red[128];
    red[j] = t * W2[j];
    __syncthreads();
    for (int off = 64; off > 0; off >>= 1) {
        if (j < off) red[j] += red[j + off];
        __syncthreads();
    }
    if (j == 0) out[b] = red[0] + b2[0];
}

extern "C" void kernel_launch(void* const* d_in, const int* in_sizes, int n_in,
                              void* d_out, int out_size, void* d_ws, size_t ws_size,
                              hipStream_t stream) {
    const float* x      = (const float*)d_in[0];
    const float* pos    = (const float*)d_in[1];
    const int*   ei     = (const int*)d_in[2];
    const int*   batch  = (const int*)d_in[3];
    const float* emb_W  = (const float*)d_in[4];
    const float* emb_b  = (const float*)d_in[5];
    const float* msg_W1 = (const float*)d_in[6];
    const float* msg_b1 = (const float*)d_in[7];
    const float* msg_W2 = (const float*)d_in[8];
    const float* msg_b2 = (const float*)d_in[9];
    const float* upd_W1 = (const float*)d_in[10];
    const float* upd_b1 = (const float*)d_in[11];
    const float* upd_W2 = (const float*)d_in[12];
    const float* upd_b2 = (const float*)d_in[13];
    const float* msg_g1 = (const float*)d_in[14];
    const float* msg_be1= (const float*)d_in[15];
    const float* msg_g2 = (const float*)d_in[16];
    const float* msg_be2= (const float*)d_in[17];
    const float* upd_g1 = (const float*)d_in[18];
    const float* upd_be1= (const float*)d_in[19];
    const float* upd_g2 = (const float*)d_in[20];
    const float* upd_be2= (const float*)d_in[21];
    const float* pred_W1= (const float*)d_in[22];
    const float* pred_b1= (const float*)d_in[23];
    const float* pred_W2= (const float*)d_in[24];
    const float* pred_b2= (const float*)d_in[25];
    float* out = (float*)d_out;

    float* ws = (float*)d_ws;
    float*     h      = ws;                           // 3.2M floats
    _Float16*  U      = (_Float16*)(ws + 3200000);    // 3.2M halves
    _Float16*  S      = (_Float16*)(ws + 4800000);    // 3.2M halves
    float*     agg    = ws + 6400000;                 // 3.2M floats
    _Float16*  usW    = (_Float16*)(ws + 9600000);    // 5 x 32768 halves
    _Float16*  eW2    = usW + DEPTH * 32768;          // 5 x 16384
    _Float16*  uW1    = eW2 + DEPTH * 16384;          // 5 x 32768
    _Float16*  uW2    = uW1 + DEPTH * 32768;          // 5 x 16384
    int*       rowptr = (int*)(ws + 19200000);        // 25,008
    int*       cursor = rowptr + 25008;               // 25,008 (doubles as cnt)
    int*       src_s  = cursor + 25008;               // 200,000
    int*       dst_s  = src_s + 200000;               // 200,000
    float*     dist_s = (float*)(dst_s + 200000);     // 200,000
    float*     g      = dist_s + 200000;              // 8,192

    hipMemsetAsync(cursor, 0, 25001 * sizeof(int), stream);
    hist_kernel<<<(N_EDGES + 255) / 256, 256, 0, stream>>>(ei, cursor);
    scan_kernel<<<1, 1024, 0, stream>>>(cursor, rowptr, cursor);
    scatter_kernel<<<(N_EDGES + 255) / 256, 256, 0, stream>>>(ei, pos, cursor, src_s, dst_s, dist_s);
    prep_kernel<<<1920, 256, 0, stream>>>(msg_W1, msg_W2, upd_W1, upd_W2, usW, eW2, uW1, uW2);

    embed_kernel<<<4096, 256, 0, stream>>>(x, emb_W, emb_b, h);

    for (int l = 0; l < DEPTH; l++) {
        const float* W1l = msg_W1 + (size_t)l * 257 * 128;
        us_kernel<<<256, 512, 0, stream>>>(h, usW + (size_t)l * 32768, msg_b1 + l * 128, U, S, agg);
        edge_kernel<<<768, 256, 0, stream>>>(
            U, S, dist_s, src_s, dst_s,
            W1l + 256 * 128, msg_g1 + l * 128, msg_be1 + l * 128,
            eW2 + (size_t)l * 16384, msg_b2 + l * 128, msg_g2 + l * 128, msg_be2 + l * 128,
            agg);
        upd_kernel<<<256, 512, 0, stream>>>(
            h, agg,
            uW1 + (size_t)l * 32768, upd_b1 + l * 128, upd_g1 + l * 128, upd_be1 + l * 128,
            uW2 + (size_t)l * 16384, upd_b2 + l * 128, upd_g2 + l * 128, upd_be2 + l * 128);
    }

    hipMemsetAsync(g, 0, N_GRAPHS * 128 * sizeof(float), stream);
    pool_kernel<<<200, 256, 0, stream>>>(h, batch, g);
    pred_kernel<<<64, 128, 0, stream>>>(g, pred_W1, pred_b1, pred_W2, pred_b2, out);
}

// Round 13
// 824.035 us; speedup vs baseline: 1.2087x; 1.2087x over previous
//
#include <hip/hip_runtime.h>
#include <hip/hip_bf16.h>

#define N_NODES 25000
#define N_EDGES 200000
#define N_GRAPHS 64
#define HID 128
#define DEPTH 5

typedef _Float16 half8 __attribute__((ext_vector_type(8)));
typedef _Float16 half2v __attribute__((ext_vector_type(2)));
typedef float f32x4 __attribute__((ext_vector_type(4)));

__device__ inline half8 pack8(float4 a, float4 b) {
    half8 r;
    r[0] = (_Float16)a.x; r[1] = (_Float16)a.y; r[2] = (_Float16)a.z; r[3] = (_Float16)a.w;
    r[4] = (_Float16)b.x; r[5] = (_Float16)b.y; r[6] = (_Float16)b.z; r[7] = (_Float16)b.w;
    return r;
}

// ---------------- embed ----------------
__global__ void embed_kernel(const float* __restrict__ x, const float* __restrict__ W,
                             const float* __restrict__ b, float* __restrict__ h) {
    for (int i = blockIdx.x * blockDim.x + threadIdx.x; i < N_NODES * HID;
         i += gridDim.x * blockDim.x) {
        int n = i >> 7, j = i & 127;
        float acc = b[j];
        #pragma unroll
        for (int k = 0; k < 16; k++) acc += x[n * 16 + k] * W[k * 128 + j];
        h[i] = acc;
    }
}

// ---------------- weight prep: f32 -> f16 arenas in EXACT LDS image layouts ----------------
__global__ void prep_kernel(const float* __restrict__ msg_W1, const float* __restrict__ msg_W2,
                            const float* __restrict__ upd_W1, const float* __restrict__ upd_W2,
                            _Float16* __restrict__ usW, _Float16* __restrict__ eW2,
                            _Float16* __restrict__ uW1, _Float16* __restrict__ uW2) {
    int i = blockIdx.x * blockDim.x + threadIdx.x;
    const int N_US = DEPTH * 32768, N_E2 = DEPTH * 16384, N_U1 = DEPTH * 32768, N_U2 = DEPTH * 16384;
    if (i < N_US) {
        int l = i >> 15, r = i & 32767;
        int j = r & 7, low6 = (r >> 3) & 63, kq = (low6 >> 4) & 3, s_ = low6 & 15;
        int rest = r >> 9, tt = rest & 15, kb = rest >> 4;
        int kk = (kb << 5) | (kq << 3) | j;
        int uh = tt >> 3, t = tt & 7, cc = s_ * 8 + t;
        const float* W1 = msg_W1 + (size_t)l * 257 * 128;
        usW[i] = (_Float16)(uh ? W1[(128 + kk) * 128 + cc] : W1[kk * 128 + cc]);
        return;
    }
    i -= N_US;
    if (i < N_E2) {
        int l = i >> 14, r = i & 16383;
        int j = r & 7, low6 = (r >> 3) & 63, kq = (low6 >> 4) & 3, s_ = low6 & 15;
        int rest = r >> 9, t = rest & 7, kb = rest >> 3;
        int k = (kb << 5) | (kq << 3) | j, c = s_ * 8 + t;
        eW2[i] = (_Float16)msg_W2[(size_t)l * 16384 + k * 128 + c];
        return;
    }
    i -= N_E2;
    if (i < N_U1) {
        int l = i >> 15, r = i & 32767;
        int j = r & 7, low6 = (r >> 3) & 63, kq = (low6 >> 4) & 3, s_ = low6 & 15;
        int rest = r >> 9, t = rest & 7, kb = rest >> 3;   // kb 0..7
        int k = (kb << 5) | (kq << 3) | j, c = s_ * 8 + t;
        uW1[i] = (_Float16)upd_W1[(size_t)l * 32768 + k * 128 + c];
        return;
    }
    i -= N_U1;
    if (i < N_U2) {
        int l = i >> 14, r = i & 16383;
        int j = r & 7, low6 = (r >> 3) & 63, kq = (low6 >> 4) & 3, s_ = low6 & 15;
        int rest = r >> 9, t = rest & 7, kb = rest >> 3;
        int k = (kb << 5) | (kq << 3) | j, c = s_ * 8 + t;
        uW2[i] = (_Float16)upd_W2[(size_t)l * 16384 + k * 128 + c];
    }
}

// ---------------- CSR build ----------------
__global__ void hist_kernel(const int* __restrict__ ei, int* __restrict__ cnt) {
    int e = blockIdx.x * blockDim.x + threadIdx.x;
    if (e < N_EDGES) atomicAdd(&cnt[ei[N_EDGES + e]], 1);
}

__global__ __launch_bounds__(1024)
void scan_kernel(const int* cnt, int* rowptr, int* cursor) {   // cnt may alias cursor
    __shared__ int swsum[16];
    __shared__ int stot;
    const int tid = threadIdx.x, wave = tid >> 6, lane = tid & 63;
    int carry = 0;
    for (int base = 0; base < N_NODES; base += 1024) {
        int i = base + tid;
        int v0 = (i < N_NODES) ? cnt[i] : 0;
        int v = v0;
        #pragma unroll
        for (int d = 1; d < 64; d <<= 1) {
            int t = __shfl_up(v, d, 64);
            if (lane >= d) v += t;
        }
        if (lane == 63) swsum[wave] = v;
        __syncthreads();
        if (wave == 0) {
            int sv = (lane < 16) ? swsum[lane] : 0;
            int si = sv;
            #pragma unroll
            for (int d = 1; d < 16; d <<= 1) {
                int t = __shfl_up(si, d, 64);
                if (lane >= d) si += t;
            }
            if (lane < 16) swsum[lane] = si - sv;
            if (lane == 15) stot = si;
        }
        __syncthreads();
        int excl = v - v0 + swsum[wave] + carry;
        if (i < N_NODES) { rowptr[i] = excl; cursor[i] = excl; }
        carry += stot;
        __syncthreads();
    }
    if (tid == 0) rowptr[N_NODES] = carry;
}

__global__ void scatter_kernel(const int* __restrict__ ei, const float* __restrict__ pos,
                               int* __restrict__ cursor, int* __restrict__ src_s,
                               int* __restrict__ dst_s, float* __restrict__ dist_s) {
    int e = blockIdx.x * blockDim.x + threadIdx.x;
    if (e < N_EDGES) {
        int s = ei[e], d = ei[N_EDGES + e];
        int p = atomicAdd(&cursor[d], 1);
        src_s[p] = s; dst_s[p] = d;
        float dx = pos[d * 3 + 0] - pos[s * 3 + 0];
        float dy = pos[d * 3 + 1] - pos[s * 3 + 1];
        float dz = pos[d * 3 + 2] - pos[s * 3 + 2];
        dist_s[p] = sqrtf(dx * dx + dy * dy + dz * dz);
    }
}

// ---------------- US precompute (arena-staged f16 weights) + agg zeroing ----------------
__global__ __launch_bounds__(512, 2)
void us_kernel(const float* __restrict__ h, const _Float16* __restrict__ Wf,
               const float* __restrict__ bias1,
               _Float16* __restrict__ U, _Float16* __restrict__ S,
               float* __restrict__ agg) {
    __shared__ __attribute__((aligned(16))) _Float16 sW[32768];   // [kb(4)][tt(16)][lane(64)][j(8)]
    __shared__ float sB1[128];
    const int tid = threadIdx.x;
    {
        const half8* wsrc = (const half8*)Wf;
        half8* wdst = (half8*)sW;
        #pragma unroll
        for (int idx = tid; idx < 4096; idx += 512) wdst[idx] = wsrc[idx];
    }
    if (tid < 128) sB1[tid] = bias1[tid];
    __syncthreads();

    const int w = tid >> 6, lane = tid & 63, quad = lane >> 4, s = lane & 15;
    float b1c[8];
    #pragma unroll
    for (int t = 0; t < 8; t++) b1c[t] = sB1[s * 8 + t];

    const int gw = blockIdx.x * 8 + w, nwaves = gridDim.x * 8;
    const int nwt = (N_NODES + 15) >> 4;
    for (int wt = gw; wt < nwt; wt += nwaves) {
        const int nbase = wt << 4;
        int n = nbase + s; if (n >= N_NODES) n = N_NODES - 1;

        half8 af[4];
        #pragma unroll
        for (int kb = 0; kb < 4; kb++) {
            const float* rp = h + (size_t)n * 128 + kb * 32 + quad * 8;
            af[kb] = pack8(*(const float4*)rp, *(const float4*)(rp + 4));
        }

        #pragma unroll
        for (int uhalf = 0; uhalf < 2; uhalf++) {
            f32x4 acc[8];
            #pragma unroll
            for (int t = 0; t < 8; t++) { f32x4 z = {0.f, 0.f, 0.f, 0.f}; acc[t] = z; }
            #pragma unroll
            for (int kb = 0; kb < 4; kb++) {
                #pragma unroll
                for (int t = 0; t < 8; t++) {
                    half8 bf = *(const half8*)(&sW[((((kb << 4) + (uhalf * 8 + t)) << 6) + lane) * 8]);
                    acc[t] = __builtin_amdgcn_mfma_f32_16x16x32_f16(af[kb], bf, acc[t], 0, 0, 0);
                }
            }
            _Float16* dstbuf = uhalf ? S : U;
            #pragma unroll
            for (int r = 0; r < 4; r++) {
                int nn = nbase + quad * 4 + r;
                if (nn < N_NODES) {
                    half8 ov;
                    #pragma unroll
                    for (int t = 0; t < 8; t++)
                        ov[t] = (_Float16)(acc[t][r] + (uhalf ? 0.f : b1c[t]));
                    *(half8*)(&dstbuf[(size_t)nn * 128 + s * 8]) = ov;
                    if (uhalf == 0) {
                        // zero agg for this node's column slice (replaces hipMemsetAsync)
                        float4 z4 = {0.f, 0.f, 0.f, 0.f};
                        float* ap = agg + (size_t)nn * 128 + s * 8;
                        *(float4*)ap = z4;
                        *(float4*)(ap + 4) = z4;
                    }
                }
            }
        }
    }
}

// ---------------- edge kernel: M=32/wave (r11 locality sweet spot), run-segmented scatter ----------------
// N_EDGES % 32 == 0 -> all 32-edge tiles are exact.
__global__ __launch_bounds__(256, 2)
void edge_kernel(const _Float16* __restrict__ U, const _Float16* __restrict__ S,
                 const float* __restrict__ dist_s, const int* __restrict__ src_s,
                 const int* __restrict__ dst_s,
                 const float* __restrict__ w256, const float* __restrict__ gam1,
                 const float* __restrict__ bet1,
                 const _Float16* __restrict__ W2f, const float* __restrict__ bias2,
                 const float* __restrict__ gam2, const float* __restrict__ bet2,
                 float* __restrict__ agg) {
    __shared__ __attribute__((aligned(16))) _Float16 sW2[16384];  // [kb(4)][t(8)][lane(64)][j(8)]
    __shared__ _Float16 sM1[17408];    // 4 waves x [32 rows][136]
    __shared__ int   sDstA[4][34];
    __shared__ int   sSrcA[4][32];
    __shared__ float sDistA[4][32];
    __shared__ float sB[768];

    const int tid = threadIdx.x;
    {
        const half8* wsrc = (const half8*)W2f;
        half8* wdst = (half8*)sW2;
        #pragma unroll
        for (int idx = tid; idx < 2048; idx += 256) wdst[idx] = wsrc[idx];
    }
    if (tid < 128) {
        sB[tid] = w256[tid];
        sB[128 + tid] = gam1[tid]; sB[256 + tid] = bet1[tid];
        sB[384 + tid] = bias2[tid]; sB[512 + tid] = gam2[tid]; sB[640 + tid] = bet2[tid];
    }
    __syncthreads();

    const int w = tid >> 6, lane = tid & 63, quad = lane >> 4, s = lane & 15;
    _Float16* myM1 = &sM1[w * (32 * 136)];
    int*   sDst  = sDstA[w];
    int*   sSrc  = sSrcA[w];
    float* sDist = sDistA[w];

    float w256c[8], g1c[8], be1c[8], b2c[8], g2c[8], be2c[8];
    #pragma unroll
    for (int t = 0; t < 8; t++) {
        int c = s * 8 + t;
        w256c[t] = sB[c]; g1c[t] = sB[128 + c]; be1c[t] = sB[256 + c];
        b2c[t] = sB[384 + c]; g2c[t] = sB[512 + c]; be2c[t] = sB[640 + c];
    }

    const int gw = blockIdx.x * 4 + w, nwaves = gridDim.x * 4;
    const int ewt = N_EDGES >> 5;   // exact
    for (int wt = gw; wt < ewt; wt += nwaves) {
        const int ebase = wt << 5;

        // phase 0: stage indices/dists into per-wave LDS (one coalesced pass)
        if (lane <= 32) {
            int e = ebase + lane;
            sDst[lane] = (e < N_EDGES) ? dst_s[e] : -1;
        } else {
            sSrc[lane - 33] = src_s[ebase + lane - 33];   // rows 0..30
        }
        if (lane < 32) sDist[lane] = dist_s[ebase + lane];
        else if (lane == 32) sSrc[31] = src_s[ebase + 31];
        bool bnd = (lane < 32) && (sDst[lane] != sDst[lane + 1]);
        unsigned mask = (unsigned)(__ballot(bnd) & 0xffffffffull);
        mask |= 0x80000000u;   // always flush at tile end (runs spanning tiles)

        // phase A: gather U/S rows (16 outstanding 16B loads)
        float distA[8];
        half8 u8A[8], s8A[8];
        #pragma unroll
        for (int i = 0; i < 8; i++) {
            int row = (i >> 2) * 16 + quad * 4 + (i & 3);
            int d = sDst[row], si = sSrc[row];
            distA[i] = sDist[row];
            u8A[i] = *(const half8*)(&U[(size_t)d * 128 + s * 8]);
            s8A[i] = *(const half8*)(&S[(size_t)si * 128 + s * 8]);
        }

        // phase B: LN + relu -> myM1 (per-wave; in-order DS pipe, no barrier)
        #pragma unroll
        for (int i = 0; i < 8; i++) {
            float v[8], sum = 0.f, sq = 0.f;
            #pragma unroll
            for (int t = 0; t < 8; t++) {
                v[t] = (float)u8A[i][t] + (float)s8A[i][t] + distA[i] * w256c[t];
                sum += v[t]; sq += v[t] * v[t];
            }
            #pragma unroll
            for (int m = 1; m < 16; m <<= 1) {
                sum += __shfl_xor(sum, m, 64);
                sq  += __shfl_xor(sq, m, 64);
            }
            float mean = sum * (1.f / 128.f);
            float var = sq * (1.f / 128.f) - mean * mean;
            float rstd = rsqrtf(var + 1e-5f);
            half8 hv;
            #pragma unroll
            for (int t = 0; t < 8; t++) {
                float y = (v[t] - mean) * rstd * g1c[t] + be1c[t];
                hv[t] = (_Float16)fmaxf(y, 0.f);
            }
            *(half8*)(&myM1[((i >> 2) * 16 + quad * 4 + (i & 3)) * 136 + s * 8]) = hv;
        }

        // GEMM2
        f32x4 acc2[2][8];
        #pragma unroll
        for (int mt = 0; mt < 2; mt++)
            #pragma unroll
            for (int t = 0; t < 8; t++) { f32x4 z = {0.f, 0.f, 0.f, 0.f}; acc2[mt][t] = z; }
        #pragma unroll
        for (int kb = 0; kb < 4; kb++) {
            half8 af[2];
            #pragma unroll
            for (int mt = 0; mt < 2; mt++)
                af[mt] = *(const half8*)(&myM1[(mt * 16 + s) * 136 + kb * 32 + quad * 8]);
            #pragma unroll
            for (int t = 0; t < 8; t++) {
                half8 bf = *(const half8*)(&sW2[(((kb << 3) + t) * 64 + lane) * 8]);
                acc2[0][t] = __builtin_amdgcn_mfma_f32_16x16x32_f16(af[0], bf, acc2[0][t], 0, 0, 0);
                acc2[1][t] = __builtin_amdgcn_mfma_f32_16x16x32_f16(af[1], bf, acc2[1][t], 0, 0, 0);
            }
        }

        // epilogue 2: LN ; relu ; m2 rows -> myM1
        #pragma unroll
        for (int mt = 0; mt < 2; mt++) {
            #pragma unroll
            for (int r = 0; r < 4; r++) {
                float v[8], sum = 0.f, sq = 0.f;
                #pragma unroll
                for (int t = 0; t < 8; t++) {
                    v[t] = acc2[mt][t][r] + b2c[t];
                    sum += v[t]; sq += v[t] * v[t];
                }
                #pragma unroll
                for (int m = 1; m < 16; m <<= 1) {
                    sum += __shfl_xor(sum, m, 64);
                    sq  += __shfl_xor(sq, m, 64);
                }
                float mean = sum * (1.f / 128.f);
                float var = sq * (1.f / 128.f) - mean * mean;
                float rstd = rsqrtf(var + 1e-5f);
                half8 hv;
                #pragma unroll
                for (int t = 0; t < 8; t++) {
                    float y = (v[t] - mean) * rstd * g2c[t] + be2c[t];
                    hv[t] = (_Float16)fmaxf(y, 0.f);
                }
                *(half8*)(&myM1[(mt * 16 + quad * 4 + r) * 136 + s * 8]) = hv;
            }
        }

        // phase C: run-segmented reduction; lane owns cols {2*lane, 2*lane+1}
        {
            const int col2 = lane * 2;
            half2v acc; acc[0] = (_Float16)0.f; acc[1] = (_Float16)0.f;
            for (int row = 0; row < 32; row++) {
                half2v v = *(const half2v*)(&myM1[row * 136 + col2]);
                acc += v;
                if ((mask >> row) & 1u) {                 // wave-uniform
                    int d = sDst[row];                    // LDS broadcast
                    float a0 = (float)acc[0], a1 = (float)acc[1];
                    if (a0 != 0.f) atomicAdd(&agg[(size_t)d * 128 + col2], a0);
                    if (a1 != 0.f) atomicAdd(&agg[(size_t)d * 128 + col2 + 1], a1);
                    acc[0] = (_Float16)0.f; acc[1] = (_Float16)0.f;
                }
            }
        }
    }
}

// ---------------- upd: node-MLP + residual (arena-staged f16 weights) ----------------
__global__ __launch_bounds__(512, 1)
void upd_kernel(float* __restrict__ h, const float* __restrict__ agg,
                const _Float16* __restrict__ W1f, const float* __restrict__ bias1,
                const float* __restrict__ gam1, const float* __restrict__ bet1,
                const _Float16* __restrict__ W2f, const float* __restrict__ bias2,
                const float* __restrict__ gam2, const float* __restrict__ bet2) {
    __shared__ __attribute__((aligned(16))) _Float16 sW1[32768];
    __shared__ __attribute__((aligned(16))) _Float16 sW2[16384];
    __shared__ _Float16 sM1[17408];   // 8 waves x [16 rows][136]
    __shared__ float sB[768];

    const int tid = threadIdx.x;
    {
        const half8* w1src = (const half8*)W1f;
        half8* w1dst = (half8*)sW1;
        #pragma unroll
        for (int idx = tid; idx < 4096; idx += 512) w1dst[idx] = w1src[idx];
        const half8* w2src = (const half8*)W2f;
        half8* w2dst = (half8*)sW2;
        #pragma unroll
        for (int idx = tid; idx < 2048; idx += 512) w2dst[idx] = w2src[idx];
    }
    if (tid < 128) {
        sB[tid] = bias1[tid]; sB[128 + tid] = gam1[tid]; sB[256 + tid] = bet1[tid];
        sB[384 + tid] = bias2[tid]; sB[512 + tid] = gam2[tid]; sB[640 + tid] = bet2[tid];
    }
    __syncthreads();

    const int w = tid >> 6, lane = tid & 63, quad = lane >> 4, s = lane & 15;
    _Float16* myM1 = &sM1[w * (16 * 136)];

    float b1c[8], g1c[8], be1c[8], b2c[8], g2c[8], be2c[8];
    #pragma unroll
    for (int t = 0; t < 8; t++) {
        int c = s * 8 + t;
        b1c[t] = sB[c]; g1c[t] = sB[128 + c]; be1c[t] = sB[256 + c];
        b2c[t] = sB[384 + c]; g2c[t] = sB[512 + c]; be2c[t] = sB[640 + c];
    }

    const int gw = blockIdx.x * 8 + w, nwaves = gridDim.x * 8;
    const int nwt = (N_NODES + 15) >> 4;
    for (int wt = gw; wt < nwt; wt += nwaves) {
        const int nbase = wt << 4;
        int n = nbase + s; if (n >= N_NODES) n = N_NODES - 1;

        // GEMM1: A = [h[n] | agg[n]] straight from global f32
        f32x4 acc[8];
        #pragma unroll
        for (int t = 0; t < 8; t++) { f32x4 z = {0.f, 0.f, 0.f, 0.f}; acc[t] = z; }
        #pragma unroll
        for (int kb = 0; kb < 8; kb++) {
            const float* rp = (kb < 4) ? (h + (size_t)n * 128 + kb * 32 + quad * 8)
                                       : (agg + (size_t)n * 128 + (kb - 4) * 32 + quad * 8);
            half8 af = pack8(*(const float4*)rp, *(const float4*)(rp + 4));
            #pragma unroll
            for (int t = 0; t < 8; t++) {
                half8 bf = *(const half8*)(&sW1[(((kb << 3) + t) * 64 + lane) * 8]);
                acc[t] = __builtin_amdgcn_mfma_f32_16x16x32_f16(af, bf, acc[t], 0, 0, 0);
            }
        }

        // epilogue 1: LN ; relu ; -> myM1
        #pragma unroll
        for (int r = 0; r < 4; r++) {
            float v[8], sum = 0.f, sq = 0.f;
            #pragma unroll
            for (int t = 0; t < 8; t++) {
                v[t] = acc[t][r] + b1c[t];
                sum += v[t]; sq += v[t] * v[t];
            }
            #pragma unroll
            for (int m = 1; m < 16; m <<= 1) {
                sum += __shfl_xor(sum, m, 64);
                sq  += __shfl_xor(sq, m, 64);
            }
            float mean = sum * (1.f / 128.f);
            float var = sq * (1.f / 128.f) - mean * mean;
            float rstd = rsqrtf(var + 1e-5f);
            half8 hv;
            #pragma unroll
            for (int t = 0; t < 8; t++) {
                float y = (v[t] - mean) * rstd * g1c[t] + be1c[t];
                hv[t] = (_Float16)fmaxf(y, 0.f);
            }
            *(half8*)(&myM1[(quad * 4 + r) * 136 + s * 8]) = hv;
        }

        // GEMM2
        f32x4 acc2[8];
        #pragma unroll
        for (int t = 0; t < 8; t++) { f32x4 z = {0.f, 0.f, 0.f, 0.f}; acc2[t] = z; }
        #pragma unroll
        for (int kb = 0; kb < 4; kb++) {
            half8 af = *(const half8*)(&myM1[s * 136 + kb * 32 + quad * 8]);
            #pragma unroll
            for (int t = 0; t < 8; t++) {
                half8 bf = *(const half8*)(&sW2[(((kb << 3) + t) * 64 + lane) * 8]);
                acc2[t] = __builtin_amdgcn_mfma_f32_16x16x32_f16(af, bf, acc2[t], 0, 0, 0);
            }
        }

        // epilogue 2: LN ; relu ; h += u
        #pragma unroll
        for (int r = 0; r < 4; r++) {
            int nn = nbase + quad * 4 + r;
            float v[8], sum = 0.f, sq = 0.f;
            #pragma unroll
            for (int t = 0; t < 8; t++) {
                v[t] = acc2[t][r] + b2c[t];
                sum += v[t]; sq += v[t] * v[t];
            }
            #pragma unroll
            for (int m = 1; m < 16; m <<= 1) {
                sum += __shfl_xor(sum, m, 64);
                sq  += __shfl_xor(sq, m, 64);
            }
            float mean = sum * (1.f / 128.f);
            float var = sq * (1.f / 128.f) - mean * mean;
            float rstd = rsqrtf(var + 1e-5f);
            if (nn < N_NODES) {
                float* hp = h + (size_t)nn * 128 + s * 8;
                float4 h0 = *(float4*)hp;
                float4 h1 = *(float4*)(hp + 4);
                float y[8];
                #pragma unroll
                for (int t = 0; t < 8; t++) {
                    float u = (v[t] - mean) * rstd * g2c[t] + be2c[t];
                    y[t] = fmaxf(u, 0.f);
                }
                h0.x += y[0]; h0.y += y[1]; h0.z += y[2]; h0.w += y[3];
                h1.x += y[4]; h1.y += y[5]; h1.z += y[6]; h1.w += y[7];
                *(float4*)hp = h0;
                *(float4*)(hp + 4) = h1;
            }
        }
    }
}

// ---------------- pool (parallel, segmented + atomics) ----------------
__global__ void pool_kernel(const float* __restrict__ h, const int* __restrict__ batch,
                            float* __restrict__ g) {
    const int CHUNK = 125;
    int blo = blockIdx.x * CHUNK;
    int bhi = blo + CHUNK; if (bhi > N_NODES) bhi = N_NODES;
    int j = threadIdx.x & 127;
    int half = threadIdx.x >> 7;
    float acc = 0.f; int cur = -1;
    for (int n = blo + half; n < bhi; n += 2) {
        int b = batch[n];
        if (b != cur) {
            if (cur >= 0) atomicAdd(&g[cur * 128 + j], acc);
            cur = b; acc = 0.f;
        }
        acc += h[(size_t)n * 128 + j];
    }
    if (cur >= 0) atomicAdd(&g[cur * 128 + j], acc);
}

// ---------------- pred ----------------
__global__ void pred_kernel(const float* __restrict__ g, const float* __restrict__ W1,
                            const float* __restrict__ b1, const float* __restrict__ W2,
                            const float* __restrict__ b2, float* __restrict__ out) {
    int b = blockIdx.x, j = threadIdx.x;
    float t = b1[j];
    for (int k = 0; k < 128; k++) t += g[b * 128 + k] * W1[k * 128 + j];
    t = fmaxf(t, 0.f);
    __shared__ float red[128];
    red[j] = t * W2[j];
    __syncthreads();
    for (int off = 64; off > 0; off >>= 1) {
        if (j < off) red[j] += red[j + off];
        __syncthreads();
    }
    if (j == 0) out[b] = red[0] + b2[0];
}

extern "C" void kernel_launch(void* const* d_in, const int* in_sizes, int n_in,
                              void* d_out, int out_size, void* d_ws, size_t ws_size,
                              hipStream_t stream) {
    const float* x      = (const float*)d_in[0];
    const float* pos    = (const float*)d_in[1];
    const int*   ei     = (const int*)d_in[2];
    const int*   batch  = (const int*)d_in[3];
    const float* emb_W  = (const float*)d_in[4];
    const float* emb_b  = (const float*)d_in[5];
    const float* msg_W1 = (const float*)d_in[6];
    const float* msg_b1 = (const float*)d_in[7];
    const float* msg_W2 = (const float*)d_in[8];
    const float* msg_b2 = (const float*)d_in[9];
    const float* upd_W1 = (const float*)d_in[10];
    const float* upd_b1 = (const float*)d_in[11];
    const float* upd_W2 = (const float*)d_in[12];
    const float* upd_b2 = (const float*)d_in[13];
    const float* msg_g1 = (const float*)d_in[14];
    const float* msg_be1= (const float*)d_in[15];
    const float* msg_g2 = (const float*)d_in[16];
    const float* msg_be2= (const float*)d_in[17];
    const float* upd_g1 = (const float*)d_in[18];
    const float* upd_be1= (const float*)d_in[19];
    const float* upd_g2 = (const float*)d_in[20];
    const float* upd_be2= (const float*)d_in[21];
    const float* pred_W1= (const float*)d_in[22];
    const float* pred_b1= (const float*)d_in[23];
    const float* pred_W2= (const float*)d_in[24];
    const float* pred_b2= (const float*)d_in[25];
    float* out = (float*)d_out;

    float* ws = (float*)d_ws;
    float*     h      = ws;                           // 3.2M floats
    _Float16*  U      = (_Float16*)(ws + 3200000);    // 3.2M halves
    _Float16*  S      = (_Float16*)(ws + 4800000);    // 3.2M halves
    float*     agg    = ws + 6400000;                 // 3.2M floats
    _Float16*  usW    = (_Float16*)(ws + 9600000);    // 5 x 32768 halves
    _Float16*  eW2    = usW + DEPTH * 32768;          // 5 x 16384
    _Float16*  uW1    = eW2 + DEPTH * 16384;          // 5 x 32768
    _Float16*  uW2    = uW1 + DEPTH * 32768;          // 5 x 16384
    int*       rowptr = (int*)(ws + 19200000);        // 25,008
    int*       cursor = rowptr + 25008;               // 25,008 (doubles as cnt)
    int*       src_s  = cursor + 25008;               // 200,000
    int*       dst_s  = src_s + 200000;               // 200,000
    float*     dist_s = (float*)(dst_s + 200000);     // 200,000
    float*     g      = dist_s + 200000;              // 8,192

    hipMemsetAsync(cursor, 0, 25001 * sizeof(int), stream);
    hist_kernel<<<(N_EDGES + 255) / 256, 256, 0, stream>>>(ei, cursor);
    scan_kernel<<<1, 1024, 0, stream>>>(cursor, rowptr, cursor);
    scatter_kernel<<<(N_EDGES + 255) / 256, 256, 0, stream>>>(ei, pos, cursor, src_s, dst_s, dist_s);
    prep_kernel<<<1920, 256, 0, stream>>>(msg_W1, msg_W2, upd_W1, upd_W2, usW, eW2, uW1, uW2);

    embed_kernel<<<4096, 256, 0, stream>>>(x, emb_W, emb_b, h);

    for (int l = 0; l < DEPTH; l++) {
        const float* W1l = msg_W1 + (size_t)l * 257 * 128;
        us_kernel<<<256, 512, 0, stream>>>(h, usW + (size_t)l * 32768, msg_b1 + l * 128, U, S, agg);
        edge_kernel<<<512, 256, 0, stream>>>(
            U, S, dist_s, src_s, dst_s,
            W1l + 256 * 128, msg_g1 + l * 128, msg_be1 + l * 128,
            eW2 + (size_t)l * 16384, msg_b2 + l * 128, msg_g2 + l * 128, msg_be2 + l * 128,
            agg);
        upd_kernel<<<256, 512, 0, stream>>>(
            h, agg,
            uW1 + (size_t)l * 32768, upd_b1 + l * 128, upd_g1 + l * 128, upd_be1 + l * 128,
            uW2 + (size_t)l * 16384, upd_b2 + l * 128, upd_g2 + l * 128, upd_be2 + l * 128);
    }

    hipMemsetAsync(g, 0, N_GRAPHS * 128 * sizeof(float), stream);
    pool_kernel<<<200, 256, 0, stream>>>(h, batch, g);
    pred_kernel<<<64, 128, 0, stream>>>(g, pred_W1, pred_b1, pred_W2, pred_b2, out);
}

// Round 14
// 580.114 us; speedup vs baseline: 1.7169x; 1.4205x over previous
//
#include <hip/hip_runtime.h>
#include <hip/hip_bf16.h>

#define N_NODES 25000
#define N_EDGES 200000
#define N_GRAPHS 64
#define HID 128
#define DEPTH 5

typedef _Float16 half8 __attribute__((ext_vector_type(8)));
typedef _Float16 half2v __attribute__((ext_vector_type(2)));
typedef float f32x4 __attribute__((ext_vector_type(4)));

__device__ inline half8 pack8(float4 a, float4 b) {
    half8 r;
    r[0] = (_Float16)a.x; r[1] = (_Float16)a.y; r[2] = (_Float16)a.z; r[3] = (_Float16)a.w;
    r[4] = (_Float16)b.x; r[5] = (_Float16)b.y; r[6] = (_Float16)b.z; r[7] = (_Float16)b.w;
    return r;
}

// ---------------- embed ----------------
__global__ void embed_kernel(const float* __restrict__ x, const float* __restrict__ W,
                             const float* __restrict__ b, float* __restrict__ h) {
    for (int i = blockIdx.x * blockDim.x + threadIdx.x; i < N_NODES * HID;
         i += gridDim.x * blockDim.x) {
        int n = i >> 7, j = i & 127;
        float acc = b[j];
        #pragma unroll
        for (int k = 0; k < 16; k++) acc += x[n * 16 + k] * W[k * 128 + j];
        h[i] = acc;
    }
}

// ---------------- weight prep: f32 -> f16 arenas in EXACT LDS image layouts ----------------
__global__ void prep_kernel(const float* __restrict__ msg_W1, const float* __restrict__ msg_W2,
                            const float* __restrict__ upd_W1, const float* __restrict__ upd_W2,
                            _Float16* __restrict__ usW, _Float16* __restrict__ eW2,
                            _Float16* __restrict__ uW1, _Float16* __restrict__ uW2) {
    int i = blockIdx.x * blockDim.x + threadIdx.x;
    const int N_US = DEPTH * 32768, N_E2 = DEPTH * 16384, N_U1 = DEPTH * 32768, N_U2 = DEPTH * 16384;
    if (i < N_US) {
        int l = i >> 15, r = i & 32767;
        int j = r & 7, low6 = (r >> 3) & 63, kq = (low6 >> 4) & 3, s_ = low6 & 15;
        int rest = r >> 9, tt = rest & 15, kb = rest >> 4;
        int kk = (kb << 5) | (kq << 3) | j;
        int uh = tt >> 3, t = tt & 7, cc = s_ * 8 + t;
        const float* W1 = msg_W1 + (size_t)l * 257 * 128;
        usW[i] = (_Float16)(uh ? W1[(128 + kk) * 128 + cc] : W1[kk * 128 + cc]);
        return;
    }
    i -= N_US;
    if (i < N_E2) {
        int l = i >> 14, r = i & 16383;
        int j = r & 7, low6 = (r >> 3) & 63, kq = (low6 >> 4) & 3, s_ = low6 & 15;
        int rest = r >> 9, t = rest & 7, kb = rest >> 3;
        int k = (kb << 5) | (kq << 3) | j, c = s_ * 8 + t;
        eW2[i] = (_Float16)msg_W2[(size_t)l * 16384 + k * 128 + c];
        return;
    }
    i -= N_E2;
    if (i < N_U1) {
        int l = i >> 15, r = i & 32767;
        int j = r & 7, low6 = (r >> 3) & 63, kq = (low6 >> 4) & 3, s_ = low6 & 15;
        int rest = r >> 9, t = rest & 7, kb = rest >> 3;   // kb 0..7
        int k = (kb << 5) | (kq << 3) | j, c = s_ * 8 + t;
        uW1[i] = (_Float16)upd_W1[(size_t)l * 32768 + k * 128 + c];
        return;
    }
    i -= N_U1;
    if (i < N_U2) {
        int l = i >> 14, r = i & 16383;
        int j = r & 7, low6 = (r >> 3) & 63, kq = (low6 >> 4) & 3, s_ = low6 & 15;
        int rest = r >> 9, t = rest & 7, kb = rest >> 3;
        int k = (kb << 5) | (kq << 3) | j, c = s_ * 8 + t;
        uW2[i] = (_Float16)upd_W2[(size_t)l * 16384 + k * 128 + c];
    }
}

// ---------------- CSR build ----------------
__global__ void hist_kernel(const int* __restrict__ ei, int* __restrict__ cnt) {
    int e = blockIdx.x * blockDim.x + threadIdx.x;
    if (e < N_EDGES) atomicAdd(&cnt[ei[N_EDGES + e]], 1);
}

__global__ __launch_bounds__(1024)
void scan_kernel(const int* cnt, int* rowptr, int* cursor) {   // cnt may alias cursor
    __shared__ int swsum[16];
    __shared__ int stot;
    const int tid = threadIdx.x, wave = tid >> 6, lane = tid & 63;
    int carry = 0;
    for (int base = 0; base < N_NODES; base += 1024) {
        int i = base + tid;
        int v0 = (i < N_NODES) ? cnt[i] : 0;
        int v = v0;
        #pragma unroll
        for (int d = 1; d < 64; d <<= 1) {
            int t = __shfl_up(v, d, 64);
            if (lane >= d) v += t;
        }
        if (lane == 63) swsum[wave] = v;
        __syncthreads();
        if (wave == 0) {
            int sv = (lane < 16) ? swsum[lane] : 0;
            int si = sv;
            #pragma unroll
            for (int d = 1; d < 16; d <<= 1) {
                int t = __shfl_up(si, d, 64);
                if (lane >= d) si += t;
            }
            if (lane < 16) swsum[lane] = si - sv;
            if (lane == 15) stot = si;
        }
        __syncthreads();
        int excl = v - v0 + swsum[wave] + carry;
        if (i < N_NODES) { rowptr[i] = excl; cursor[i] = excl; }
        carry += stot;
        __syncthreads();
    }
    if (tid == 0) rowptr[N_NODES] = carry;
}

__global__ void scatter_kernel(const int* __restrict__ ei, const float* __restrict__ pos,
                               int* __restrict__ cursor, int* __restrict__ src_s,
                               int* __restrict__ dst_s, float* __restrict__ dist_s) {
    int e = blockIdx.x * blockDim.x + threadIdx.x;
    if (e < N_EDGES) {
        int s = ei[e], d = ei[N_EDGES + e];
        int p = atomicAdd(&cursor[d], 1);
        src_s[p] = s; dst_s[p] = d;
        float dx = pos[d * 3 + 0] - pos[s * 3 + 0];
        float dy = pos[d * 3 + 1] - pos[s * 3 + 1];
        float dz = pos[d * 3 + 2] - pos[s * 3 + 2];
        dist_s[p] = sqrtf(dx * dx + dy * dy + dz * dz);
    }
}

// ---------------- US precompute (layer 0 only) + agg zeroing ----------------
__global__ __launch_bounds__(512, 2)
void us_kernel(const float* __restrict__ h, const _Float16* __restrict__ Wf,
               const float* __restrict__ bias1,
               _Float16* __restrict__ U, _Float16* __restrict__ S,
               float* __restrict__ agg) {
    __shared__ __attribute__((aligned(16))) _Float16 sW[32768];   // [kb(4)][tt(16)][lane(64)][j(8)]
    __shared__ float sB1[128];
    const int tid = threadIdx.x;
    {
        const half8* wsrc = (const half8*)Wf;
        half8* wdst = (half8*)sW;
        #pragma unroll
        for (int idx = tid; idx < 4096; idx += 512) wdst[idx] = wsrc[idx];
    }
    if (tid < 128) sB1[tid] = bias1[tid];
    __syncthreads();

    const int w = tid >> 6, lane = tid & 63, quad = lane >> 4, s = lane & 15;
    float b1c[8];
    #pragma unroll
    for (int t = 0; t < 8; t++) b1c[t] = sB1[s * 8 + t];

    const int gw = blockIdx.x * 8 + w, nwaves = gridDim.x * 8;
    const int nwt = (N_NODES + 15) >> 4;
    for (int wt = gw; wt < nwt; wt += nwaves) {
        const int nbase = wt << 4;
        int n = nbase + s; if (n >= N_NODES) n = N_NODES - 1;

        half8 af[4];
        #pragma unroll
        for (int kb = 0; kb < 4; kb++) {
            const float* rp = h + (size_t)n * 128 + kb * 32 + quad * 8;
            af[kb] = pack8(*(const float4*)rp, *(const float4*)(rp + 4));
        }

        #pragma unroll
        for (int uhalf = 0; uhalf < 2; uhalf++) {
            f32x4 acc[8];
            #pragma unroll
            for (int t = 0; t < 8; t++) { f32x4 z = {0.f, 0.f, 0.f, 0.f}; acc[t] = z; }
            #pragma unroll
            for (int kb = 0; kb < 4; kb++) {
                #pragma unroll
                for (int t = 0; t < 8; t++) {
                    half8 bf = *(const half8*)(&sW[((((kb << 4) + (uhalf * 8 + t)) << 6) + lane) * 8]);
                    acc[t] = __builtin_amdgcn_mfma_f32_16x16x32_f16(af[kb], bf, acc[t], 0, 0, 0);
                }
            }
            _Float16* dstbuf = uhalf ? S : U;
            #pragma unroll
            for (int r = 0; r < 4; r++) {
                int nn = nbase + quad * 4 + r;
                if (nn < N_NODES) {
                    half8 ov;
                    #pragma unroll
                    for (int t = 0; t < 8; t++)
                        ov[t] = (_Float16)(acc[t][r] + (uhalf ? 0.f : b1c[t]));
                    *(half8*)(&dstbuf[(size_t)nn * 128 + s * 8]) = ov;
                    if (uhalf == 0) {
                        float4 z4 = {0.f, 0.f, 0.f, 0.f};
                        float* ap = agg + (size_t)nn * 128 + s * 8;
                        *(float4*)ap = z4;
                        *(float4*)(ap + 4) = z4;
                    }
                }
            }
        }
    }
}

// ---------------- edge kernel: M=32/wave, run-segmented scatter ----------------
__global__ __launch_bounds__(256, 2)
void edge_kernel(const _Float16* __restrict__ U, const _Float16* __restrict__ S,
                 const float* __restrict__ dist_s, const int* __restrict__ src_s,
                 const int* __restrict__ dst_s,
                 const float* __restrict__ w256, const float* __restrict__ gam1,
                 const float* __restrict__ bet1,
                 const _Float16* __restrict__ W2f, const float* __restrict__ bias2,
                 const float* __restrict__ gam2, const float* __restrict__ bet2,
                 float* __restrict__ agg) {
    __shared__ __attribute__((aligned(16))) _Float16 sW2[16384];  // [kb(4)][t(8)][lane(64)][j(8)]
    __shared__ _Float16 sM1[17408];    // 4 waves x [32 rows][136]
    __shared__ int   sDstA[4][34];
    __shared__ int   sSrcA[4][32];
    __shared__ float sDistA[4][32];
    __shared__ float sB[768];

    const int tid = threadIdx.x;
    {
        const half8* wsrc = (const half8*)W2f;
        half8* wdst = (half8*)sW2;
        #pragma unroll
        for (int idx = tid; idx < 2048; idx += 256) wdst[idx] = wsrc[idx];
    }
    if (tid < 128) {
        sB[tid] = w256[tid];
        sB[128 + tid] = gam1[tid]; sB[256 + tid] = bet1[tid];
        sB[384 + tid] = bias2[tid]; sB[512 + tid] = gam2[tid]; sB[640 + tid] = bet2[tid];
    }
    __syncthreads();

    const int w = tid >> 6, lane = tid & 63, quad = lane >> 4, s = lane & 15;
    _Float16* myM1 = &sM1[w * (32 * 136)];
    int*   sDst  = sDstA[w];
    int*   sSrc  = sSrcA[w];
    float* sDist = sDistA[w];

    float w256c[8], g1c[8], be1c[8], b2c[8], g2c[8], be2c[8];
    #pragma unroll
    for (int t = 0; t < 8; t++) {
        int c = s * 8 + t;
        w256c[t] = sB[c]; g1c[t] = sB[128 + c]; be1c[t] = sB[256 + c];
        b2c[t] = sB[384 + c]; g2c[t] = sB[512 + c]; be2c[t] = sB[640 + c];
    }

    const int gw = blockIdx.x * 4 + w, nwaves = gridDim.x * 4;
    const int ewt = N_EDGES >> 5;   // exact
    for (int wt = gw; wt < ewt; wt += nwaves) {
        const int ebase = wt << 5;

        // phase 0: stage indices/dists into per-wave LDS
        if (lane <= 32) {
            int e = ebase + lane;
            sDst[lane] = (e < N_EDGES) ? dst_s[e] : -1;
        } else {
            sSrc[lane - 33] = src_s[ebase + lane - 33];   // rows 0..30
        }
        if (lane < 32) sDist[lane] = dist_s[ebase + lane];
        else if (lane == 32) sSrc[31] = src_s[ebase + 31];
        bool bnd = (lane < 32) && (sDst[lane] != sDst[lane + 1]);
        unsigned mask = (unsigned)(__ballot(bnd) & 0xffffffffull);
        mask |= 0x80000000u;   // always flush at tile end

        // phase A: gather U/S rows
        float distA[8];
        half8 u8A[8], s8A[8];
        #pragma unroll
        for (int i = 0; i < 8; i++) {
            int row = (i >> 2) * 16 + quad * 4 + (i & 3);
            int d = sDst[row], si = sSrc[row];
            distA[i] = sDist[row];
            u8A[i] = *(const half8*)(&U[(size_t)d * 128 + s * 8]);
            s8A[i] = *(const half8*)(&S[(size_t)si * 128 + s * 8]);
        }

        // phase B: LN + relu -> myM1
        #pragma unroll
        for (int i = 0; i < 8; i++) {
            float v[8], sum = 0.f, sq = 0.f;
            #pragma unroll
            for (int t = 0; t < 8; t++) {
                v[t] = (float)u8A[i][t] + (float)s8A[i][t] + distA[i] * w256c[t];
                sum += v[t]; sq += v[t] * v[t];
            }
            #pragma unroll
            for (int m = 1; m < 16; m <<= 1) {
                sum += __shfl_xor(sum, m, 64);
                sq  += __shfl_xor(sq, m, 64);
            }
            float mean = sum * (1.f / 128.f);
            float var = sq * (1.f / 128.f) - mean * mean;
            float rstd = rsqrtf(var + 1e-5f);
            half8 hv;
            #pragma unroll
            for (int t = 0; t < 8; t++) {
                float y = (v[t] - mean) * rstd * g1c[t] + be1c[t];
                hv[t] = (_Float16)fmaxf(y, 0.f);
            }
            *(half8*)(&myM1[((i >> 2) * 16 + quad * 4 + (i & 3)) * 136 + s * 8]) = hv;
        }

        // GEMM2
        f32x4 acc2[2][8];
        #pragma unroll
        for (int mt = 0; mt < 2; mt++)
            #pragma unroll
            for (int t = 0; t < 8; t++) { f32x4 z = {0.f, 0.f, 0.f, 0.f}; acc2[mt][t] = z; }
        #pragma unroll
        for (int kb = 0; kb < 4; kb++) {
            half8 af[2];
            #pragma unroll
            for (int mt = 0; mt < 2; mt++)
                af[mt] = *(const half8*)(&myM1[(mt * 16 + s) * 136 + kb * 32 + quad * 8]);
            #pragma unroll
            for (int t = 0; t < 8; t++) {
                half8 bf = *(const half8*)(&sW2[(((kb << 3) + t) * 64 + lane) * 8]);
                acc2[0][t] = __builtin_amdgcn_mfma_f32_16x16x32_f16(af[0], bf, acc2[0][t], 0, 0, 0);
                acc2[1][t] = __builtin_amdgcn_mfma_f32_16x16x32_f16(af[1], bf, acc2[1][t], 0, 0, 0);
            }
        }

        // epilogue 2: LN ; relu ; m2 rows -> myM1
        #pragma unroll
        for (int mt = 0; mt < 2; mt++) {
            #pragma unroll
            for (int r = 0; r < 4; r++) {
                float v[8], sum = 0.f, sq = 0.f;
                #pragma unroll
                for (int t = 0; t < 8; t++) {
                    v[t] = acc2[mt][t][r] + b2c[t];
                    sum += v[t]; sq += v[t] * v[t];
                }
                #pragma unroll
                for (int m = 1; m < 16; m <<= 1) {
                    sum += __shfl_xor(sum, m, 64);
                    sq  += __shfl_xor(sq, m, 64);
                }
                float mean = sum * (1.f / 128.f);
                float var = sq * (1.f / 128.f) - mean * mean;
                float rstd = rsqrtf(var + 1e-5f);
                half8 hv;
                #pragma unroll
                for (int t = 0; t < 8; t++) {
                    float y = (v[t] - mean) * rstd * g2c[t] + be2c[t];
                    hv[t] = (_Float16)fmaxf(y, 0.f);
                }
                *(half8*)(&myM1[(mt * 16 + quad * 4 + r) * 136 + s * 8]) = hv;
            }
        }

        // phase C: run-segmented reduction
        {
            const int col2 = lane * 2;
            half2v acc; acc[0] = (_Float16)0.f; acc[1] = (_Float16)0.f;
            for (int row = 0; row < 32; row++) {
                half2v v = *(const half2v*)(&myM1[row * 136 + col2]);
                acc += v;
                if ((mask >> row) & 1u) {                 // wave-uniform
                    int d = sDst[row];
                    float a0 = (float)acc[0], a1 = (float)acc[1];
                    if (a0 != 0.f) atomicAdd(&agg[(size_t)d * 128 + col2], a0);
                    if (a1 != 0.f) atomicAdd(&agg[(size_t)d * 128 + col2 + 1], a1);
                    acc[0] = (_Float16)0.f; acc[1] = (_Float16)0.f;
                }
            }
        }
    }
}

// ---------------- upd: node-MLP + residual + FUSED next-layer U/S + agg re-zero ----------------
// One tile (16 nodes) per wave; grid 256 x 8 waves >= 1563 tiles.
__global__ __launch_bounds__(512, 1)
void upd_kernel(float* __restrict__ h, float* __restrict__ agg,
                const _Float16* __restrict__ W1f, const float* __restrict__ bias1,
                const float* __restrict__ gam1, const float* __restrict__ bet1,
                const _Float16* __restrict__ W2f, const float* __restrict__ bias2,
                const float* __restrict__ gam2, const float* __restrict__ bet2,
                const _Float16* __restrict__ usWf, const float* __restrict__ nb1,
                _Float16* __restrict__ U, _Float16* __restrict__ S, int do_us) {
    __shared__ __attribute__((aligned(16))) _Float16 sW1[32768];
    __shared__ __attribute__((aligned(16))) _Float16 sW2[16384];
    __shared__ _Float16 sM1[17408];   // 8 waves x [16 rows][136]
    __shared__ float sB[768];

    const int tid = threadIdx.x;
    {
        const half8* w1src = (const half8*)W1f;
        half8* w1dst = (half8*)sW1;
        #pragma unroll
        for (int idx = tid; idx < 4096; idx += 512) w1dst[idx] = w1src[idx];
        const half8* w2src = (const half8*)W2f;
        half8* w2dst = (half8*)sW2;
        #pragma unroll
        for (int idx = tid; idx < 2048; idx += 512) w2dst[idx] = w2src[idx];
    }
    if (tid < 128) {
        sB[tid] = bias1[tid]; sB[128 + tid] = gam1[tid]; sB[256 + tid] = bet1[tid];
        sB[384 + tid] = bias2[tid]; sB[512 + tid] = gam2[tid]; sB[640 + tid] = bet2[tid];
    }
    __syncthreads();

    const int w = tid >> 6, lane = tid & 63, quad = lane >> 4, s = lane & 15;
    _Float16* myM1 = &sM1[w * (16 * 136)];

    const int wt = blockIdx.x * 8 + w;
    const int nwt = (N_NODES + 15) >> 4;
    const bool active = (wt < nwt);
    const int nbase = wt << 4;

    if (active) {
        float b1c[8], g1c[8], be1c[8], b2c[8], g2c[8], be2c[8];
        #pragma unroll
        for (int t = 0; t < 8; t++) {
            int c = s * 8 + t;
            b1c[t] = sB[c]; g1c[t] = sB[128 + c]; be1c[t] = sB[256 + c];
            b2c[t] = sB[384 + c]; g2c[t] = sB[512 + c]; be2c[t] = sB[640 + c];
        }
        int n = nbase + s; if (n >= N_NODES) n = N_NODES - 1;

        // GEMM1: A = [h[n] | agg[n]]
        f32x4 acc[8];
        #pragma unroll
        for (int t = 0; t < 8; t++) { f32x4 z = {0.f, 0.f, 0.f, 0.f}; acc[t] = z; }
        #pragma unroll
        for (int kb = 0; kb < 8; kb++) {
            const float* rp = (kb < 4) ? (h + (size_t)n * 128 + kb * 32 + quad * 8)
                                       : (agg + (size_t)n * 128 + (kb - 4) * 32 + quad * 8);
            half8 af = pack8(*(const float4*)rp, *(const float4*)(rp + 4));
            #pragma unroll
            for (int t = 0; t < 8; t++) {
                half8 bf = *(const half8*)(&sW1[(((kb << 3) + t) * 64 + lane) * 8]);
                acc[t] = __builtin_amdgcn_mfma_f32_16x16x32_f16(af, bf, acc[t], 0, 0, 0);
            }
        }

        // epilogue 1: LN ; relu ; -> myM1
        #pragma unroll
        for (int r = 0; r < 4; r++) {
            float v[8], sum = 0.f, sq = 0.f;
            #pragma unroll
            for (int t = 0; t < 8; t++) {
                v[t] = acc[t][r] + b1c[t];
                sum += v[t]; sq += v[t] * v[t];
            }
            #pragma unroll
            for (int m = 1; m < 16; m <<= 1) {
                sum += __shfl_xor(sum, m, 64);
                sq  += __shfl_xor(sq, m, 64);
            }
            float mean = sum * (1.f / 128.f);
            float var = sq * (1.f / 128.f) - mean * mean;
            float rstd = rsqrtf(var + 1e-5f);
            half8 hv;
            #pragma unroll
            for (int t = 0; t < 8; t++) {
                float y = (v[t] - mean) * rstd * g1c[t] + be1c[t];
                hv[t] = (_Float16)fmaxf(y, 0.f);
            }
            *(half8*)(&myM1[(quad * 4 + r) * 136 + s * 8]) = hv;
        }

        // GEMM2
        f32x4 acc2[8];
        #pragma unroll
        for (int t = 0; t < 8; t++) { f32x4 z = {0.f, 0.f, 0.f, 0.f}; acc2[t] = z; }
        #pragma unroll
        for (int kb = 0; kb < 4; kb++) {
            half8 af = *(const half8*)(&myM1[s * 136 + kb * 32 + quad * 8]);
            #pragma unroll
            for (int t = 0; t < 8; t++) {
                half8 bf = *(const half8*)(&sW2[(((kb << 3) + t) * 64 + lane) * 8]);
                acc2[t] = __builtin_amdgcn_mfma_f32_16x16x32_f16(af, bf, acc2[t], 0, 0, 0);
            }
        }

        // epilogue 2: LN ; relu ; h += u ; keep h_new f16 in myM1 (for fused U/S)
        #pragma unroll
        for (int r = 0; r < 4; r++) {
            int nn = nbase + quad * 4 + r;
            float v[8], sum = 0.f, sq = 0.f;
            #pragma unroll
            for (int t = 0; t < 8; t++) {
                v[t] = acc2[t][r] + b2c[t];
                sum += v[t]; sq += v[t] * v[t];
            }
            #pragma unroll
            for (int m = 1; m < 16; m <<= 1) {
                sum += __shfl_xor(sum, m, 64);
                sq  += __shfl_xor(sq, m, 64);
            }
            float mean = sum * (1.f / 128.f);
            float var = sq * (1.f / 128.f) - mean * mean;
            float rstd = rsqrtf(var + 1e-5f);
            if (nn < N_NODES) {
                float* hp = h + (size_t)nn * 128 + s * 8;
                float4 h0 = *(float4*)hp;
                float4 h1 = *(float4*)(hp + 4);
                float hn[8];
                #pragma unroll
                for (int t = 0; t < 8; t++) {
                    float u = (v[t] - mean) * rstd * g2c[t] + be2c[t];
                    hn[t] = fmaxf(u, 0.f);
                }
                h0.x += hn[0]; h0.y += hn[1]; h0.z += hn[2]; h0.w += hn[3];
                h1.x += hn[4]; h1.y += hn[5]; h1.z += hn[6]; h1.w += hn[7];
                *(float4*)hp = h0;
                *(float4*)(hp + 4) = h1;
                half8 hv = pack8(h0, h1);   // h_new f16, C-layout row
                *(half8*)(&myM1[(quad * 4 + r) * 136 + s * 8]) = hv;
            }
        }
    }

    if (do_us) {
        __syncthreads();   // all waves done with sW1
        {
            const half8* wsrc = (const half8*)usWf;
            half8* wdst = (half8*)sW1;
            #pragma unroll
            for (int idx = tid; idx < 4096; idx += 512) wdst[idx] = wsrc[idx];
        }
        __syncthreads();
        if (active) {
            float nb1c[8];
            #pragma unroll
            for (int t = 0; t < 8; t++) nb1c[t] = nb1[s * 8 + t];
            half8 af[4];
            #pragma unroll
            for (int kb = 0; kb < 4; kb++)
                af[kb] = *(const half8*)(&myM1[s * 136 + kb * 32 + quad * 8]);
            #pragma unroll
            for (int uhalf = 0; uhalf < 2; uhalf++) {
                f32x4 acc[8];
                #pragma unroll
                for (int t = 0; t < 8; t++) { f32x4 z = {0.f, 0.f, 0.f, 0.f}; acc[t] = z; }
                #pragma unroll
                for (int kb = 0; kb < 4; kb++) {
                    #pragma unroll
                    for (int t = 0; t < 8; t++) {
                        half8 bf = *(const half8*)(&sW1[((((kb << 4) + (uhalf * 8 + t)) << 6) + lane) * 8]);
                        acc[t] = __builtin_amdgcn_mfma_f32_16x16x32_f16(af[kb], bf, acc[t], 0, 0, 0);
                    }
                }
                _Float16* dstbuf = uhalf ? S : U;
                #pragma unroll
                for (int r = 0; r < 4; r++) {
                    int nn = nbase + quad * 4 + r;
                    if (nn < N_NODES) {
                        half8 ov;
                        #pragma unroll
                        for (int t = 0; t < 8; t++)
                            ov[t] = (_Float16)(acc[t][r] + (uhalf ? 0.f : nb1c[t]));
                        *(half8*)(&dstbuf[(size_t)nn * 128 + s * 8]) = ov;
                        if (uhalf == 0) {
                            float4 z4 = {0.f, 0.f, 0.f, 0.f};
                            float* ap = agg + (size_t)nn * 128 + s * 8;
                            *(float4*)ap = z4;
                            *(float4*)(ap + 4) = z4;
                        }
                    }
                }
            }
        }
    }
}

// ---------------- pool (parallel, segmented + atomics) ----------------
__global__ void pool_kernel(const float* __restrict__ h, const int* __restrict__ batch,
                            float* __restrict__ g) {
    const int CHUNK = 125;
    int blo = blockIdx.x * CHUNK;
    int bhi = blo + CHUNK; if (bhi > N_NODES) bhi = N_NODES;
    int j = threadIdx.x & 127;
    int half = threadIdx.x >> 7;
    float acc = 0.f; int cur = -1;
    for (int n = blo + half; n < bhi; n += 2) {
        int b = batch[n];
        if (b != cur) {
            if (cur >= 0) atomicAdd(&g[cur * 128 + j], acc);
            cur = b; acc = 0.f;
        }
        acc += h[(size_t)n * 128 + j];
    }
    if (cur >= 0) atomicAdd(&g[cur * 128 + j], acc);
}

// ---------------- pred ----------------
__global__ void pred_kernel(const float* __restrict__ g, const float* __restrict__ W1,
                            const float* __restrict__ b1, const float* __restrict__ W2,
                            const float* __restrict__ b2, float* __restrict__ out) {
    int b = blockIdx.x, j = threadIdx.x;
    float t = b1[j];
    for (int k = 0; k < 128; k++) t += g[b * 128 + k] * W1[k * 128 + j];
    t = fmaxf(t, 0.f);
    __shared__ float red[128];
    red[j] = t * W2[j];
    __syncthreads();
    for (int off = 64; off > 0; off >>= 1) {
        if (j < off) red[j] += red[j + off];
        __syncthreads();
    }
    if (j == 0) out[b] = red[0] + b2[0];
}

extern "C" void kernel_launch(void* const* d_in, const int* in_sizes, int n_in,
                              void* d_out, int out_size, void* d_ws, size_t ws_size,
                              hipStream_t stream) {
    const float* x      = (const float*)d_in[0];
    const float* pos    = (const float*)d_in[1];
    const int*   ei     = (const int*)d_in[2];
    const int*   batch  = (const int*)d_in[3];
    const float* emb_W  = (const float*)d_in[4];
    const float* emb_b  = (const float*)d_in[5];
    const float* msg_W1 = (const float*)d_in[6];
    const float* msg_b1 = (const float*)d_in[7];
    const float* msg_W2 = (const float*)d_in[8];
    const float* msg_b2 = (const float*)d_in[9];
    const float* upd_W1 = (const float*)d_in[10];
    const float* upd_b1 = (const float*)d_in[11];
    const float* upd_W2 = (const float*)d_in[12];
    const float* upd_b2 = (const float*)d_in[13];
    const float* msg_g1 = (const float*)d_in[14];
    const float* msg_be1= (const float*)d_in[15];
    const float* msg_g2 = (const float*)d_in[16];
    const float* msg_be2= (const float*)d_in[17];
    const float* upd_g1 = (const float*)d_in[18];
    const float* upd_be1= (const float*)d_in[19];
    const float* upd_g2 = (const float*)d_in[20];
    const float* upd_be2= (const float*)d_in[21];
    const float* pred_W1= (const float*)d_in[22];
    const float* pred_b1= (const float*)d_in[23];
    const float* pred_W2= (const float*)d_in[24];
    const float* pred_b2= (const float*)d_in[25];
    float* out = (float*)d_out;

    float* ws = (float*)d_ws;
    float*     h      = ws;                           // 3.2M floats
    _Float16*  U      = (_Float16*)(ws + 3200000);    // 3.2M halves
    _Float16*  S      = (_Float16*)(ws + 4800000);    // 3.2M halves
    float*     agg    = ws + 6400000;                 // 3.2M floats
    _Float16*  usW    = (_Float16*)(ws + 9600000);    // 5 x 32768 halves
    _Float16*  eW2    = usW + DEPTH * 32768;          // 5 x 16384
    _Float16*  uW1    = eW2 + DEPTH * 16384;          // 5 x 32768
    _Float16*  uW2    = uW1 + DEPTH * 32768;          // 5 x 16384
    int*       rowptr = (int*)(ws + 19200000);        // 25,008
    int*       cursor = rowptr + 25008;               // 25,008 (doubles as cnt)
    int*       src_s  = cursor + 25008;               // 200,000
    int*       dst_s  = src_s + 200000;               // 200,000
    float*     dist_s = (float*)(dst_s + 200000);     // 200,000
    float*     g      = dist_s + 200000;              // 8,192

    hipMemsetAsync(cursor, 0, 25001 * sizeof(int), stream);
    hist_kernel<<<(N_EDGES + 255) / 256, 256, 0, stream>>>(ei, cursor);
    scan_kernel<<<1, 1024, 0, stream>>>(cursor, rowptr, cursor);
    scatter_kernel<<<(N_EDGES + 255) / 256, 256, 0, stream>>>(ei, pos, cursor, src_s, dst_s, dist_s);
    prep_kernel<<<1920, 256, 0, stream>>>(msg_W1, msg_W2, upd_W1, upd_W2, usW, eW2, uW1, uW2);

    embed_kernel<<<4096, 256, 0, stream>>>(x, emb_W, emb_b, h);

    // layer-0 U/S + agg zero
    us_kernel<<<256, 512, 0, stream>>>(h, usW, msg_b1, U, S, agg);

    for (int l = 0; l < DEPTH; l++) {
        const float* W1l = msg_W1 + (size_t)l * 257 * 128;
        edge_kernel<<<512, 256, 0, stream>>>(
            U, S, dist_s, src_s, dst_s,
            W1l + 256 * 128, msg_g1 + l * 128, msg_be1 + l * 128,
            eW2 + (size_t)l * 16384, msg_b2 + l * 128, msg_g2 + l * 128, msg_be2 + l * 128,
            agg);
        int do_us = (l + 1 < DEPTH) ? 1 : 0;
        int ln = (l + 1 < DEPTH) ? (l + 1) : 0;   // dummy 0 when do_us==0
        upd_kernel<<<256, 512, 0, stream>>>(
            h, agg,
            uW1 + (size_t)l * 32768, upd_b1 + l * 128, upd_g1 + l * 128, upd_be1 + l * 128,
            uW2 + (size_t)l * 16384, upd_b2 + l * 128, upd_g2 + l * 128, upd_be2 + l * 128,
            usW + (size_t)ln * 32768, msg_b1 + ln * 128, U, S, do_us);
    }

    hipMemsetAsync(g, 0, N_GRAPHS * 128 * sizeof(float), stream);
    pool_kernel<<<200, 256, 0, stream>>>(h, batch, g);
    pred_kernel<<<64, 128, 0, stream>>>(g, pred_W1, pred_b1, pred_W2, pred_b2, out);
}